// Round 1
// 447.980 us; speedup vs baseline: 1.0033x; 1.0033x over previous
//
#include <hip/hip_runtime.h>
#include <hip/hip_bf16.h>
#include <math.h>

typedef __attribute__((ext_vector_type(8))) short short8;
typedef __attribute__((ext_vector_type(4))) short short4_t;
typedef __attribute__((ext_vector_type(4))) float f32x4;

#define Bb 2
#define Tt 2048
#define Hh 16
#define Dd 128
#define Cc 2048
#define Ff 6144

// Packed operand layout (K=2048 only): element (row,k) lives at
//   ((m_tile*64 + ks)*8 + g)*512 + (sub*16 + srow)*8 + w
// where m_tile=row>>7, g=(row>>4)&7, srow=row&15, ks=k>>5, sub=(k>>3)&3, w=k&7.
// Each 1024B granule is exactly one global_load_lds: lane l reads byte l*16 and
// LDS-writes byte l*16, giving A[g*16+(l&15)][(l>>4)*8..+7] — the MFMA fragment
// order — so staging is fully coalesced AND fragment ds_read_b128 is conflict-free.
__device__ __forceinline__ size_t packed_idx(int row, int k) {
  return ((((size_t)(row >> 7) * 64 + (k >> 5)) * 8 + ((row >> 4) & 7)) * 512)
         + ((((k >> 3) & 3) * 16 + (row & 15)) * 8) + (k & 7);
}

__device__ __forceinline__ void gload_lds16(const void* g, void* l) {
  __builtin_amdgcn_global_load_lds(
      (const __attribute__((address_space(1))) void*)g,
      (__attribute__((address_space(3))) void*)l, 16, 0, 0);
}

// fp32 row-major (rows x 2048) -> bf16 packed layout. One thread per 16B output
// chunk (8 elements); writes coalesced, reads 16 x 128B segments per wave.
__global__ __launch_bounds__(256) void pack_cast(
    const float* __restrict__ in, __hip_bfloat16* __restrict__ out, int n16)
{
  int t = blockIdx.x * 256 + threadIdx.x;
  if (t >= n16) return;
  int l = t & 63;
  int granule_lin = t >> 6;
  int g = granule_lin & 7;
  int slab = granule_lin >> 3;
  int ks = slab & 63;          // K/32 = 64
  int m_tile = slab >> 6;
  int row = m_tile * 128 + g * 16 + (l & 15);
  int k = ks * 32 + (l >> 4) * 8;
  const float* src = in + (size_t)row * 2048 + k;
  float4 v0 = *(const float4*)src;
  float4 v1 = *(const float4*)(src + 4);
  __hip_bfloat16 tmp[8] = {
      __float2bfloat16(v0.x), __float2bfloat16(v0.y),
      __float2bfloat16(v0.z), __float2bfloat16(v0.w),
      __float2bfloat16(v1.x), __float2bfloat16(v1.y),
      __float2bfloat16(v1.z), __float2bfloat16(v1.w)};
  *(short8*)(out + (size_t)t * 8) = *(const short8*)tmp;
}

__device__ __forceinline__ void store_out(__hip_bfloat16* p, float v) { *p = __float2bfloat16(v); }
__device__ __forceinline__ void store_out(float* p, float v) { *p = v; }

// C (MxN row-major) = A * B^T with A (MxK), B (NxK) BOTH in packed layout above.
// 128x128x32 tile, 16 KB LDS (8 blocks/CU), granule LDS layout: staging loads
// are 1KB contiguous, fragment reads conflict-free.
template <typename OutT>
__global__ __launch_bounds__(256) void gemm_pk(
    const __hip_bfloat16* __restrict__ Ap,
    const __hip_bfloat16* __restrict__ Bp,
    OutT* __restrict__ Cm,
    int K, int N)
{
  __shared__ __align__(16) __hip_bfloat16 As[128 * 32];
  __shared__ __align__(16) __hip_bfloat16 Bs[128 * 32];
  const int tid  = threadIdx.x;
  const int wave = tid >> 6;
  const int lane = tid & 63;
  const int quad = lane >> 4;
  const int l16  = lane & 15;
  const int bm = blockIdx.y * 128;
  const int bn = blockIdx.x * 128;
  const int wm4 = (wave >> 1) * 4;   // granule base of this wave's M range
  const int wn4 = (wave & 1) * 4;    // granule base of this wave's N range
  const int KS = K >> 5;

  f32x4 acc[4][4];
#pragma unroll
  for (int i = 0; i < 4; i++)
#pragma unroll
    for (int j = 0; j < 4; j++)
#pragma unroll
      for (int r = 0; r < 4; r++) acc[i][j][r] = 0.f;

  // Hoisted staging pointers: wave stages granules wave*2, wave*2+1 (1KB each,
  // contiguous: lane l reads byte l*16).
  const char* pA[2];
  const char* pB[2];
#pragma unroll
  for (int c = 0; c < 2; c++) {
    int g = wave * 2 + c;
    pA[c] = (const char*)Ap + (size_t)(bm >> 7) * KS * 8192 + g * 1024 + lane * 16;
    pB[c] = (const char*)Bp + (size_t)(bn >> 7) * KS * 8192 + g * 1024 + lane * 16;
  }

  for (int ks = 0; ks < KS; ks++) {
#pragma unroll
    for (int c = 0; c < 2; c++) {
      int g = wave * 2 + c;  // wave-uniform granule id
      gload_lds16(pA[c], As + g * 512);
      gload_lds16(pB[c], Bs + g * 512);
      pA[c] += 8192;
      pB[c] += 8192;
    }
    __syncthreads();
    short8 af[4], bf[4];
#pragma unroll
    for (int i = 0; i < 4; i++)
      af[i] = *(const short8*)(As + (wm4 + i) * 512 + lane * 8);
#pragma unroll
    for (int j = 0; j < 4; j++)
      bf[j] = *(const short8*)(Bs + (wn4 + j) * 512 + lane * 8);
#pragma unroll
    for (int i = 0; i < 4; i++)
#pragma unroll
      for (int j = 0; j < 4; j++)
        acc[i][j] = __builtin_amdgcn_mfma_f32_16x16x32_bf16(af[i], bf[j], acc[i][j], 0, 0, 0);
    __syncthreads();
  }

#pragma unroll
  for (int i = 0; i < 4; i++)
#pragma unroll
    for (int j = 0; j < 4; j++)
#pragma unroll
      for (int r = 0; r < 4; r++) {
        int gm = bm + (wave >> 1) * 64 + i * 16 + quad * 4 + r;
        int gn = bn + (wave & 1) * 64 + j * 16 + l16;
        store_out(Cm + (size_t)gm * N + gn, acc[i][j][r]);
      }
}

// In-place RoPE on q,k halves of qkv. Q half additionally pre-scaled by 1/sqrt(D).
__global__ __launch_bounds__(256) void rope_qk(__hip_bfloat16* __restrict__ qkv)
{
  int tid = blockIdx.x * 256 + threadIdx.x;
  int d = tid & 63;
  int h = (tid >> 6) & 15;
  int t = (tid >> 10) & 2047;
  int bw = tid >> 21;
  int b = bw & 1, which = bw >> 1;
  size_t base = (size_t)(b * Tt + t) * Ff + which * 2048 + h * Dd + d;
  float inv = expf(-(float)d * (9.210340371976184f / 64.0f));
  float ang = (float)t * inv;
  float c = cosf(ang), s = sinf(ang);
  float x1 = __bfloat162float(qkv[base]);
  float x2 = __bfloat162float(qkv[base + 64]);
  float o1 = x1 * c - x2 * s;
  float o2 = x2 * c + x1 * s;
  if (which == 0) {
    o1 *= 0.08838834764831845f;
    o2 *= 0.08838834764831845f;
  }
  qkv[base]      = __float2bfloat16(o1);
  qkv[base + 64] = __float2bfloat16(o2);
}

// v (from qkv buffer, (b,t,h,d)) -> vt (b,h,d,t).
__global__ __launch_bounds__(256) void transpose_v(
    const __hip_bfloat16* __restrict__ qkv, __hip_bfloat16* __restrict__ vt)
{
  __shared__ __hip_bfloat16 tile[64 * 65];
  int bh = blockIdx.y;
  int dt = blockIdx.x >> 5;
  int tt = blockIdx.x & 31;
  int b = bh >> 4, h = bh & 15;
  const __hip_bfloat16* src = qkv + (size_t)(b * Tt + tt * 64) * Ff + 4096 + h * Dd + dt * 64;
#pragma unroll
  for (int i = 0; i < 16; i++) {
    int lin = i * 256 + threadIdx.x;
    int tl = lin >> 6, dc = lin & 63;
    tile[tl * 65 + dc] = src[(size_t)tl * Ff + dc];
  }
  __syncthreads();
  __hip_bfloat16* dst = vt + ((size_t)bh * Dd + dt * 64) * Tt + tt * 64;
#pragma unroll
  for (int i = 0; i < 16; i++) {
    int lin = i * 256 + threadIdx.x;
    int dr = lin >> 6, tc = lin & 63;
    dst[(size_t)dr * Tt + tc] = tile[tc * 65 + dr];
  }
}

// Flash attention v3: 512 threads (8 waves, 16 q-rows each), 128-row Q tiles,
// software-pipelined staging. One q-tile per block (512 blocks -> 2 blocks/CU,
// all co-resident). Complement mapping: block i (i<256) takes qi=p, block i+256
// takes qi=15-p, so the two blocks typically co-resident on a CU sum to the
// balanced 34 k-iterations and share bh (K/V L2 locality, same XCD via idx%8).
// Epilogue writes yat in PACKED layout (consumed by gemm_pk for the projection).
__global__ __launch_bounds__(512) void flash_attn3(
    const __hip_bfloat16* __restrict__ qkv,
    const __hip_bfloat16* __restrict__ vt,
    __hip_bfloat16* __restrict__ yat)
{
  __shared__ __align__(16) __hip_bfloat16 KsBuf[2][8192];
  __shared__ __align__(16) __hip_bfloat16 VsBuf[8192];
  __shared__ __align__(16) __hip_bfloat16 PsBuf[8 * 1088];
  const int tid  = threadIdx.x;
  const int wave = tid >> 6;          // 0..7
  const int lane = tid & 63;
  const int quad = lane >> 4;
  const int l16  = lane & 15;
  const int idx  = blockIdx.x;
  const int top  = idx >> 8;          // 0 or 1
  const int rest = idx & 255;
  const int p    = rest >> 5;         // 0..7
  const int bh   = rest & 31;
  const int qi   = top ? (15 - p) : p;
  const int b = bh >> 4, h = bh & 15;

  const char* kbase = (const char*)(qkv + (size_t)b * Tt * Ff + 2048 + h * Dd);
  const char* vbase = (const char*)(vt + (size_t)bh * Dd * Tt);
  __hip_bfloat16* Pw = PsBuf + wave * 1088;
  const int srow = lane & 15;
  const int scol = lane >> 4;

  const int qm0 = qi * 128;
  const int niter = 2 * qi + 2;

  short8 qf[4];
  {
    const __hip_bfloat16* qrow =
        qkv + (size_t)(b * Tt + qm0 + wave * 16 + l16) * Ff + h * Dd;
#pragma unroll
    for (int kc = 0; kc < 4; kc++)
      qf[kc] = *(const short8*)(qrow + kc * 32 + quad * 8);
  }

#pragma unroll
  for (int c = 0; c < 2; c++) {
    int chunk = wave * 2 + c;
    int j = chunk >> 2, kc = chunk & 3;
    const char* src = kbase + (size_t)(j * 16 + srow) * (Ff * 2) + kc * 64 + scol * 16;
    gload_lds16(src, KsBuf[0] + chunk * 512);
  }

  f32x4 oacc[8];
#pragma unroll
  for (int jd = 0; jd < 8; jd++)
#pragma unroll
    for (int r = 0; r < 4; r++) oacc[jd][r] = 0.f;
  float mrow[4], lrow[4];
#pragma unroll
  for (int r = 0; r < 4; r++) { mrow[r] = -INFINITY; lrow[r] = 0.f; }

#pragma unroll 1
  for (int kt = 0; kt < niter; ++kt) {
    __builtin_amdgcn_s_barrier();                      // A: prev iter fully done
#pragma unroll
    for (int c = 0; c < 2; c++) {
      int chunk = wave * 2 + c;
      int jd = chunk >> 1, k2 = chunk & 1;
      const char* src = vbase + (size_t)(jd * 16 + srow) * (Tt * 2) + kt * 128 + k2 * 64 + scol * 16;
      gload_lds16(src, VsBuf + chunk * 512);
    }
    if (kt + 1 < niter) {
#pragma unroll
      for (int c = 0; c < 2; c++) {
        int chunk = wave * 2 + c;
        int j = chunk >> 2, kc = chunk & 3;
        const char* src = kbase + (size_t)((kt + 1) * 64 + j * 16 + srow) * (Ff * 2) + kc * 64 + scol * 16;
        gload_lds16(src, KsBuf[(kt + 1) & 1] + chunk * 512);
      }
      __builtin_amdgcn_s_waitcnt(0xF74);  // vmcnt(4): K(kt) landed
    } else {
      __builtin_amdgcn_s_waitcnt(0xF72);  // vmcnt(2): K(kt) landed
    }
    __builtin_amdgcn_s_barrier();                      // B: K(kt) visible

    const __hip_bfloat16* KsB = KsBuf[kt & 1];
    const bool diag = (kt >= 2 * qi);

    f32x4 sacc[4];
#pragma unroll
    for (int j = 0; j < 4; j++)
#pragma unroll
      for (int r = 0; r < 4; r++) sacc[j][r] = 0.f;
#pragma unroll
    for (int j = 0; j < 4; j++)
#pragma unroll
      for (int kc = 0; kc < 4; kc++) {
        short8 kf = *(const short8*)(KsB + (j * 4 + kc) * 512 + lane * 8);
        sacc[j] = __builtin_amdgcn_mfma_f32_16x16x32_bf16(qf[kc], kf, sacc[j], 0, 0, 0);
      }
    float sv[4][4];
#pragma unroll
    for (int j = 0; j < 4; j++)
#pragma unroll
      for (int r = 0; r < 4; r++) {
        float v = sacc[j][r];
        if (diag) {
          int kg = kt * 64 + j * 16 + l16;
          int qg = qm0 + wave * 16 + quad * 4 + r;
          if (kg > qg) v = -INFINITY;
        }
        sv[j][r] = v;
      }
    float mnew[4];
#pragma unroll
    for (int r = 0; r < 4; r++)
      mnew[r] = fmaxf(fmaxf(sv[0][r], sv[1][r]), fmaxf(sv[2][r], sv[3][r]));
#pragma unroll
    for (int off = 1; off < 16; off <<= 1)
#pragma unroll
      for (int r = 0; r < 4; r++)
        mnew[r] = fmaxf(mnew[r], __shfl_xor(mnew[r], off, 64));
    float alpha[4];
#pragma unroll
    for (int r = 0; r < 4; r++) {
      float mi = fmaxf(mrow[r], mnew[r]);
      alpha[r] = __expf(mrow[r] - mi);
      mrow[r] = mi;
    }
    float rs[4] = {0.f, 0.f, 0.f, 0.f};
#pragma unroll
    for (int j = 0; j < 4; j++)
#pragma unroll
      for (int r = 0; r < 4; r++) {
        float p2 = __expf(sv[j][r] - mrow[r]);
        rs[r] += p2;
        Pw[(j * 2 + (l16 >> 3)) * 136 + (quad * 4 + r) * 8 + (l16 & 7)] = __float2bfloat16(p2);
      }
#pragma unroll
    for (int off = 1; off < 16; off <<= 1)
#pragma unroll
      for (int r = 0; r < 4; r++)
        rs[r] += __shfl_xor(rs[r], off, 64);
#pragma unroll
    for (int r = 0; r < 4; r++) lrow[r] = lrow[r] * alpha[r] + rs[r];
#pragma unroll
    for (int jd = 0; jd < 8; jd++)
#pragma unroll
      for (int r = 0; r < 4; r++) oacc[jd][r] *= alpha[r];

    if (kt + 1 < niter) {
      __builtin_amdgcn_s_waitcnt(0xF72);  // vmcnt(2): V(kt) landed
    } else {
      __builtin_amdgcn_s_waitcnt(0xF70);  // vmcnt(0)
    }
    __builtin_amdgcn_s_barrier();                      // C: V(kt) visible

#pragma unroll
    for (int k2 = 0; k2 < 2; k2++) {
      short8 pf = *(const short8*)(Pw + (k2 * 4 + quad) * 136 + l16 * 8);
#pragma unroll
      for (int jd = 0; jd < 8; jd++) {
        short8 vf = *(const short8*)(VsBuf + (jd * 2 + k2) * 512 + lane * 8);
        oacc[jd] = __builtin_amdgcn_mfma_f32_16x16x32_bf16(pf, vf, oacc[jd], 0, 0, 0);
      }
    }
  }

  // epilogue: O / l -> yat in PACKED layout (A-operand of projection GEMM)
  float linv[4];
#pragma unroll
  for (int r = 0; r < 4; r++) linv[r] = 1.f / lrow[r];
#pragma unroll
  for (int jd = 0; jd < 8; jd++)
#pragma unroll
    for (int r = 0; r < 4; r++) {
      int row = b * Tt + qm0 + wave * 16 + quad * 4 + r;
      int c = h * Dd + jd * 16 + l16;
      yat[packed_idx(row, c)] = __float2bfloat16(oacc[jd][r] * linv[r]);
    }
}

extern "C" void kernel_launch(void* const* d_in, const int* in_sizes, int n_in,
                              void* d_out, int out_size, void* d_ws, size_t ws_size,
                              hipStream_t stream) {
  (void)in_sizes; (void)n_in; (void)out_size; (void)ws_size;
  const float* x_f      = (const float*)d_in[0];
  const float* w_qkv_f  = (const float*)d_in[1];
  const float* w_proj_f = (const float*)d_in[2];
  float* out = (float*)d_out;

  char* ws = (char*)d_ws;
  __hip_bfloat16* qkv = (__hip_bfloat16*)ws;                      // 48 MiB
  __hip_bfloat16* vt  = (__hip_bfloat16*)(ws + 50331648);         // 16 MiB
  __hip_bfloat16* yat = (__hip_bfloat16*)(ws + 67108864);         // 16 MiB (packed)
  __hip_bfloat16* xb  = (__hip_bfloat16*)(ws + 83886080);         // 16 MiB (packed)
  __hip_bfloat16* wqb = (__hip_bfloat16*)(ws + 100663296);        // 24 MiB (packed)
  __hip_bfloat16* wpb = (__hip_bfloat16*)(ws + 125829120);        // 8 MiB (packed)

  // pack-cast fp32 inputs -> bf16 packed tiles (K=2048 for all three)
  pack_cast<<<4096, 256, 0, stream>>>(x_f, xb, 1048576);       // 4096 x 2048
  pack_cast<<<6144, 256, 0, stream>>>(w_qkv_f, wqb, 1572864);  // 6144 x 2048
  pack_cast<<<2048, 256, 0, stream>>>(w_proj_f, wpb, 524288);  // 2048 x 2048

  gemm_pk<__hip_bfloat16><<<dim3(48, 32), 256, 0, stream>>>(xb, wqb, qkv, 2048, 6144);
  rope_qk<<<32768, 256, 0, stream>>>(qkv);
  transpose_v<<<dim3(64, 32), 256, 0, stream>>>(qkv, vt);
  flash_attn3<<<512, 512, 0, stream>>>(qkv, vt, yat);
  gemm_pk<float><<<dim3(16, 32), 256, 0, stream>>>(yat, wpb, out, 2048, 2048);
}

// Round 2
// 437.631 us; speedup vs baseline: 1.0270x; 1.0236x over previous
//
#include <hip/hip_runtime.h>
#include <hip/hip_bf16.h>
#include <math.h>

typedef __attribute__((ext_vector_type(8))) short short8;
typedef __attribute__((ext_vector_type(4))) short short4_t;
typedef __attribute__((ext_vector_type(4))) float f32x4;

#define Bb 2
#define Tt 2048
#define Hh 16
#define Dd 128
#define Cc 2048
#define Ff 6144

// Packed operand layout (K=2048 only): element (row,k) lives at
//   ((m_tile*64 + ks)*8 + g)*512 + (sub*16 + srow)*8 + w
// where m_tile=row>>7, g=(row>>4)&7, srow=row&15, ks=k>>5, sub=(k>>3)&3, w=k&7.
// Each 1024B granule is exactly one global_load_lds: lane l reads byte l*16 and
// LDS-writes byte l*16, giving A[g*16+(l&15)][(l>>4)*8..+7] — the MFMA fragment
// order — so staging is fully coalesced AND fragment ds_read_b128 is conflict-free.
__device__ __forceinline__ size_t packed_idx(int row, int k) {
  return ((((size_t)(row >> 7) * 64 + (k >> 5)) * 8 + ((row >> 4) & 7)) * 512)
         + ((((k >> 3) & 3) * 16 + (row & 15)) * 8) + (k & 7);
}

__device__ __forceinline__ void gload_lds16(const void* g, void* l) {
  __builtin_amdgcn_global_load_lds(
      (const __attribute__((address_space(1))) void*)g,
      (__attribute__((address_space(3))) void*)l, 16, 0, 0);
}

// fp32 row-major (rows x 2048) -> bf16 packed layout. One thread per 16B output
// chunk (8 elements); writes coalesced, reads 16 x 128B segments per wave.
__global__ __launch_bounds__(256) void pack_cast(
    const float* __restrict__ in, __hip_bfloat16* __restrict__ out, int n16)
{
  int t = blockIdx.x * 256 + threadIdx.x;
  if (t >= n16) return;
  int l = t & 63;
  int granule_lin = t >> 6;
  int g = granule_lin & 7;
  int slab = granule_lin >> 3;
  int ks = slab & 63;          // K/32 = 64
  int m_tile = slab >> 6;
  int row = m_tile * 128 + g * 16 + (l & 15);
  int k = ks * 32 + (l >> 4) * 8;
  const float* src = in + (size_t)row * 2048 + k;
  float4 v0 = *(const float4*)src;
  float4 v1 = *(const float4*)(src + 4);
  __hip_bfloat16 tmp[8] = {
      __float2bfloat16(v0.x), __float2bfloat16(v0.y),
      __float2bfloat16(v0.z), __float2bfloat16(v0.w),
      __float2bfloat16(v1.x), __float2bfloat16(v1.y),
      __float2bfloat16(v1.z), __float2bfloat16(v1.w)};
  *(short8*)(out + (size_t)t * 8) = *(const short8*)tmp;
}

__device__ __forceinline__ void store_out(__hip_bfloat16* p, float v) { *p = __float2bfloat16(v); }
__device__ __forceinline__ void store_out(float* p, float v) { *p = v; }

// C (MxN row-major) = A * B^T with A (MxK), B (NxK) BOTH in packed layout above.
// 128x128x32 tile, 16 KB LDS (8 blocks/CU). Used for the projection GEMM
// (where 256^2 tiling would underfill the grid: only 128 blocks).
template <typename OutT>
__global__ __launch_bounds__(256) void gemm_pk(
    const __hip_bfloat16* __restrict__ Ap,
    const __hip_bfloat16* __restrict__ Bp,
    OutT* __restrict__ Cm,
    int K, int N)
{
  __shared__ __align__(16) __hip_bfloat16 As[128 * 32];
  __shared__ __align__(16) __hip_bfloat16 Bs[128 * 32];
  const int tid  = threadIdx.x;
  const int wave = tid >> 6;
  const int lane = tid & 63;
  const int quad = lane >> 4;
  const int l16  = lane & 15;
  const int bm = blockIdx.y * 128;
  const int bn = blockIdx.x * 128;
  const int wm4 = (wave >> 1) * 4;
  const int wn4 = (wave & 1) * 4;
  const int KS = K >> 5;

  f32x4 acc[4][4];
#pragma unroll
  for (int i = 0; i < 4; i++)
#pragma unroll
    for (int j = 0; j < 4; j++)
#pragma unroll
      for (int r = 0; r < 4; r++) acc[i][j][r] = 0.f;

  const char* pA[2];
  const char* pB[2];
#pragma unroll
  for (int c = 0; c < 2; c++) {
    int g = wave * 2 + c;
    pA[c] = (const char*)Ap + (size_t)(bm >> 7) * KS * 8192 + g * 1024 + lane * 16;
    pB[c] = (const char*)Bp + (size_t)(bn >> 7) * KS * 8192 + g * 1024 + lane * 16;
  }

  for (int ks = 0; ks < KS; ks++) {
#pragma unroll
    for (int c = 0; c < 2; c++) {
      int g = wave * 2 + c;
      gload_lds16(pA[c], As + g * 512);
      gload_lds16(pB[c], Bs + g * 512);
      pA[c] += 8192;
      pB[c] += 8192;
    }
    __syncthreads();
    short8 af[4], bf[4];
#pragma unroll
    for (int i = 0; i < 4; i++)
      af[i] = *(const short8*)(As + (wm4 + i) * 512 + lane * 8);
#pragma unroll
    for (int j = 0; j < 4; j++)
      bf[j] = *(const short8*)(Bs + (wn4 + j) * 512 + lane * 8);
#pragma unroll
    for (int i = 0; i < 4; i++)
#pragma unroll
      for (int j = 0; j < 4; j++)
        acc[i][j] = __builtin_amdgcn_mfma_f32_16x16x32_bf16(af[i], bf[j], acc[i][j], 0, 0, 0);
    __syncthreads();
  }

#pragma unroll
  for (int i = 0; i < 4; i++)
#pragma unroll
    for (int j = 0; j < 4; j++)
#pragma unroll
      for (int r = 0; r < 4; r++) {
        int gm = bm + (wave >> 1) * 64 + i * 16 + quad * 4 + r;
        int gn = bn + (wave & 1) * 64 + j * 16 + l16;
        store_out(Cm + (size_t)gm * N + gn, acc[i][j][r]);
      }
}

// 256x256 8-phase GEMM (QKV matmul), K=2048 fixed. 8 waves (2Mx4N, 128x64 each),
// BK=64, LDS = 4 half-tile slots x 32KB = 128KB ring (half = 128 A-rows + 128
// B-rows x 64k). Schedule per K-tile: 4 phases, each
//   {2 gload_lds stage | ds_read frags | barrier | setprio1 + 16 MFMA + setprio0 | barrier}
// with a single counted vmcnt(2) per tile (phase 0) — loads stay in flight
// across barriers; vmcnt(0) only on the final tile. Packed-granule layout keeps
// both staging and fragment ds_read_b128 conflict-free (T2 by construction).
#define GEMM8_PHASE(MB)                                                        \
  {                                                                            \
    short8 af[2][2];                                                           \
    _Pragma("unroll") for (int i = 0; i < 2; i++)                              \
      _Pragma("unroll") for (int k2 = 0; k2 < 2; k2++)                         \
        af[i][k2] = *(const short8*)(Ard + (k2 * 8 + MB + i) * 512 + lane * 8);\
    __builtin_amdgcn_s_barrier();                                              \
    __builtin_amdgcn_s_setprio(1);                                             \
    _Pragma("unroll") for (int i = 0; i < 2; i++)                              \
      _Pragma("unroll") for (int j = 0; j < 4; j++)                            \
        _Pragma("unroll") for (int k2 = 0; k2 < 2; k2++)                       \
          acc[MB + i][j] = __builtin_amdgcn_mfma_f32_16x16x32_bf16(            \
              af[i][k2], bf[j][k2], acc[MB + i][j], 0, 0, 0);                  \
    __builtin_amdgcn_s_setprio(0);                                             \
    __builtin_amdgcn_s_barrier();                                              \
  }

__global__ __launch_bounds__(512, 2) void gemm_pk8(
    const __hip_bfloat16* __restrict__ Ap,
    const __hip_bfloat16* __restrict__ Bp,
    __hip_bfloat16* __restrict__ Cm, int N)
{
  __shared__ __align__(16) __hip_bfloat16 L[65536];  // 4 slots x (A 8192 | B 8192) elems
  const int tid  = threadIdx.x;
  const int wave = tid >> 6;          // 0..7
  const int lane = tid & 63;
  const int quad = lane >> 4;
  const int l16  = lane & 15;
  const int wm = wave >> 2;           // 0..1
  const int wn = wave & 3;            // 0..3
  const int bm = blockIdx.y * 256;
  const int bn = blockIdx.x * 256;
  const int NT = 32;                  // K/64
  const int gl = wave * 2;            // this wave's granule pair (c=0,1) within a half
  const int rb = (wn & 1) * 4;        // B rg_off base within the wave's half

  // staging pointers (bytes), for target tile 0; advance +16384 per tile.
  const char* pA[2][2];
  const char* pB[2][2];
#pragma unroll
  for (int hh = 0; hh < 2; hh++)
#pragma unroll
    for (int c = 0; c < 2; c++) {
      int g = gl + c;
      pA[hh][c] = (const char*)Ap +
          (size_t)(((bm >> 7) + hh) * 64 + (g >> 3)) * 8192 + (g & 7) * 1024 + lane * 16;
      pB[hh][c] = (const char*)Bp +
          (size_t)(((bn >> 7) + hh) * 64 + (g >> 3)) * 8192 + (g & 7) * 1024 + lane * 16;
    }

  // prologue: stage halves 0,1 (tile 0) into slots 0,1; no drain — phase-0
  // vmcnt(2)+barrier of tile 0 provides visibility.
#pragma unroll
  for (int hh = 0; hh < 2; hh++) {
#pragma unroll
    for (int c = 0; c < 2; c++)
      gload_lds16(pA[hh][c], &L[hh * 16384 + (gl + c) * 512]);
#pragma unroll
    for (int c = 0; c < 2; c++)
      gload_lds16(pB[hh][c], &L[hh * 16384 + 8192 + (gl + c) * 512]);
  }
#pragma unroll
  for (int hh = 0; hh < 2; hh++)
#pragma unroll
    for (int c = 0; c < 2; c++) { pA[hh][c] += 16384; pB[hh][c] += 16384; }

  f32x4 acc[8][4];
#pragma unroll
  for (int i = 0; i < 8; i++)
#pragma unroll
    for (int j = 0; j < 4; j++)
#pragma unroll
      for (int r = 0; r < 4; r++) acc[i][j][r] = 0.f;

#pragma unroll 1
  for (int t = 0; t < NT; ++t) {
    const int tp = t & 1;
    const __hip_bfloat16* Ard = &L[(wm + 2 * tp) * 16384];
    const __hip_bfloat16* Brd = &L[((wn >> 1) + 2 * tp) * 16384 + 8192];
    __hip_bfloat16* wrA0 = &L[(2 - 2 * tp) * 16384];   // half 2t+2 slot
    __hip_bfloat16* wrB0 = wrA0 + 8192;
    __hip_bfloat16* wrA1 = wrA0 + 16384;               // half 2t+3 slot
    __hip_bfloat16* wrB1 = wrA1 + 8192;
    const bool pre = (t + 1 < NT);

    // ---- phase 0: stage A(half even) | vmcnt(2) | barrier | read B(8)+A(m0,m1) | MFMA
    if (pre) {
      gload_lds16(pA[0][0], wrA0 + (gl + 0) * 512);
      gload_lds16(pA[0][1], wrA0 + (gl + 1) * 512);
      __builtin_amdgcn_s_waitcnt(0xF72);  // vmcnt(2): halves 2t,2t+1 landed
    } else {
      __builtin_amdgcn_s_waitcnt(0xF70);  // vmcnt(0): tail drain
    }
    __builtin_amdgcn_s_barrier();

    short8 bf[4][2];
#pragma unroll
    for (int j = 0; j < 4; j++)
#pragma unroll
      for (int k2 = 0; k2 < 2; k2++)
        bf[j][k2] = *(const short8*)(Brd + (k2 * 8 + rb + j) * 512 + lane * 8);
    {
      short8 af[2][2];
#pragma unroll
      for (int i = 0; i < 2; i++)
#pragma unroll
        for (int k2 = 0; k2 < 2; k2++)
          af[i][k2] = *(const short8*)(Ard + (k2 * 8 + i) * 512 + lane * 8);
      __builtin_amdgcn_s_setprio(1);
#pragma unroll
      for (int i = 0; i < 2; i++)
#pragma unroll
        for (int j = 0; j < 4; j++)
#pragma unroll
          for (int k2 = 0; k2 < 2; k2++)
            acc[i][j] = __builtin_amdgcn_mfma_f32_16x16x32_bf16(
                af[i][k2], bf[j][k2], acc[i][j], 0, 0, 0);
      __builtin_amdgcn_s_setprio(0);
    }
    __builtin_amdgcn_s_barrier();

    // ---- phase 1: stage B(half even); m2,m3
    if (pre) {
      gload_lds16(pB[0][0], wrB0 + (gl + 0) * 512);
      gload_lds16(pB[0][1], wrB0 + (gl + 1) * 512);
    }
    GEMM8_PHASE(2);

    // ---- phase 2: stage A(half odd); m4,m5
    if (pre) {
      gload_lds16(pA[1][0], wrA1 + (gl + 0) * 512);
      gload_lds16(pA[1][1], wrA1 + (gl + 1) * 512);
    }
    GEMM8_PHASE(4);

    // ---- phase 3: stage B(half odd); m6,m7
    if (pre) {
      gload_lds16(pB[1][0], wrB1 + (gl + 0) * 512);
      gload_lds16(pB[1][1], wrB1 + (gl + 1) * 512);
    }
    GEMM8_PHASE(6);

    if (pre) {
#pragma unroll
      for (int hh = 0; hh < 2; hh++)
#pragma unroll
        for (int c = 0; c < 2; c++) { pA[hh][c] += 16384; pB[hh][c] += 16384; }
    }
  }

#pragma unroll
  for (int i = 0; i < 8; i++)
#pragma unroll
    for (int j = 0; j < 4; j++)
#pragma unroll
      for (int r = 0; r < 4; r++) {
        int gm = bm + wm * 128 + i * 16 + quad * 4 + r;
        int gn = bn + wn * 64 + j * 16 + l16;
        Cm[(size_t)gm * N + gn] = __float2bfloat16(acc[i][j][r]);
      }
}

// In-place RoPE on q,k halves of qkv. Q half additionally pre-scaled by 1/sqrt(D).
__global__ __launch_bounds__(256) void rope_qk(__hip_bfloat16* __restrict__ qkv)
{
  int tid = blockIdx.x * 256 + threadIdx.x;
  int d = tid & 63;
  int h = (tid >> 6) & 15;
  int t = (tid >> 10) & 2047;
  int bw = tid >> 21;
  int b = bw & 1, which = bw >> 1;
  size_t base = (size_t)(b * Tt + t) * Ff + which * 2048 + h * Dd + d;
  float inv = expf(-(float)d * (9.210340371976184f / 64.0f));
  float ang = (float)t * inv;
  float c = cosf(ang), s = sinf(ang);
  float x1 = __bfloat162float(qkv[base]);
  float x2 = __bfloat162float(qkv[base + 64]);
  float o1 = x1 * c - x2 * s;
  float o2 = x2 * c + x1 * s;
  if (which == 0) {
    o1 *= 0.08838834764831845f;
    o2 *= 0.08838834764831845f;
  }
  qkv[base]      = __float2bfloat16(o1);
  qkv[base + 64] = __float2bfloat16(o2);
}

// v (from qkv buffer, (b,t,h,d)) -> vt (b,h,d,t).
__global__ __launch_bounds__(256) void transpose_v(
    const __hip_bfloat16* __restrict__ qkv, __hip_bfloat16* __restrict__ vt)
{
  __shared__ __hip_bfloat16 tile[64 * 65];
  int bh = blockIdx.y;
  int dt = blockIdx.x >> 5;
  int tt = blockIdx.x & 31;
  int b = bh >> 4, h = bh & 15;
  const __hip_bfloat16* src = qkv + (size_t)(b * Tt + tt * 64) * Ff + 4096 + h * Dd + dt * 64;
#pragma unroll
  for (int i = 0; i < 16; i++) {
    int lin = i * 256 + threadIdx.x;
    int tl = lin >> 6, dc = lin & 63;
    tile[tl * 65 + dc] = src[(size_t)tl * Ff + dc];
  }
  __syncthreads();
  __hip_bfloat16* dst = vt + ((size_t)bh * Dd + dt * 64) * Tt + tt * 64;
#pragma unroll
  for (int i = 0; i < 16; i++) {
    int lin = i * 256 + threadIdx.x;
    int dr = lin >> 6, tc = lin & 63;
    dst[(size_t)dr * Tt + tc] = tile[tc * 65 + dr];
  }
}

// Flash attention v3: 512 threads (8 waves, 16 q-rows each), 128-row Q tiles,
// software-pipelined staging. One q-tile per block (512 blocks -> 2 blocks/CU).
__global__ __launch_bounds__(512) void flash_attn3(
    const __hip_bfloat16* __restrict__ qkv,
    const __hip_bfloat16* __restrict__ vt,
    __hip_bfloat16* __restrict__ yat)
{
  __shared__ __align__(16) __hip_bfloat16 KsBuf[2][8192];
  __shared__ __align__(16) __hip_bfloat16 VsBuf[8192];
  __shared__ __align__(16) __hip_bfloat16 PsBuf[8 * 1088];
  const int tid  = threadIdx.x;
  const int wave = tid >> 6;          // 0..7
  const int lane = tid & 63;
  const int quad = lane >> 4;
  const int l16  = lane & 15;
  const int idx  = blockIdx.x;
  const int top  = idx >> 8;          // 0 or 1
  const int rest = idx & 255;
  const int p    = rest >> 5;         // 0..7
  const int bh   = rest & 31;
  const int qi   = top ? (15 - p) : p;
  const int b = bh >> 4, h = bh & 15;

  const char* kbase = (const char*)(qkv + (size_t)b * Tt * Ff + 2048 + h * Dd);
  const char* vbase = (const char*)(vt + (size_t)bh * Dd * Tt);
  __hip_bfloat16* Pw = PsBuf + wave * 1088;
  const int srow = lane & 15;
  const int scol = lane >> 4;

  const int qm0 = qi * 128;
  const int niter = 2 * qi + 2;

  short8 qf[4];
  {
    const __hip_bfloat16* qrow =
        qkv + (size_t)(b * Tt + qm0 + wave * 16 + l16) * Ff + h * Dd;
#pragma unroll
    for (int kc = 0; kc < 4; kc++)
      qf[kc] = *(const short8*)(qrow + kc * 32 + quad * 8);
  }

#pragma unroll
  for (int c = 0; c < 2; c++) {
    int chunk = wave * 2 + c;
    int j = chunk >> 2, kc = chunk & 3;
    const char* src = kbase + (size_t)(j * 16 + srow) * (Ff * 2) + kc * 64 + scol * 16;
    gload_lds16(src, KsBuf[0] + chunk * 512);
  }

  f32x4 oacc[8];
#pragma unroll
  for (int jd = 0; jd < 8; jd++)
#pragma unroll
    for (int r = 0; r < 4; r++) oacc[jd][r] = 0.f;
  float mrow[4], lrow[4];
#pragma unroll
  for (int r = 0; r < 4; r++) { mrow[r] = -INFINITY; lrow[r] = 0.f; }

#pragma unroll 1
  for (int kt = 0; kt < niter; ++kt) {
    __builtin_amdgcn_s_barrier();                      // A: prev iter fully done
#pragma unroll
    for (int c = 0; c < 2; c++) {
      int chunk = wave * 2 + c;
      int jd = chunk >> 1, k2 = chunk & 1;
      const char* src = vbase + (size_t)(jd * 16 + srow) * (Tt * 2) + kt * 128 + k2 * 64 + scol * 16;
      gload_lds16(src, VsBuf + chunk * 512);
    }
    if (kt + 1 < niter) {
#pragma unroll
      for (int c = 0; c < 2; c++) {
        int chunk = wave * 2 + c;
        int j = chunk >> 2, kc = chunk & 3;
        const char* src = kbase + (size_t)((kt + 1) * 64 + j * 16 + srow) * (Ff * 2) + kc * 64 + scol * 16;
        gload_lds16(src, KsBuf[(kt + 1) & 1] + chunk * 512);
      }
      __builtin_amdgcn_s_waitcnt(0xF74);  // vmcnt(4): K(kt) landed
    } else {
      __builtin_amdgcn_s_waitcnt(0xF72);  // vmcnt(2): K(kt) landed
    }
    __builtin_amdgcn_s_barrier();                      // B: K(kt) visible

    const __hip_bfloat16* KsB = KsBuf[kt & 1];
    const bool diag = (kt >= 2 * qi);

    f32x4 sacc[4];
#pragma unroll
    for (int j = 0; j < 4; j++)
#pragma unroll
      for (int r = 0; r < 4; r++) sacc[j][r] = 0.f;
#pragma unroll
    for (int j = 0; j < 4; j++)
#pragma unroll
      for (int kc = 0; kc < 4; kc++) {
        short8 kf = *(const short8*)(KsB + (j * 4 + kc) * 512 + lane * 8);
        sacc[j] = __builtin_amdgcn_mfma_f32_16x16x32_bf16(qf[kc], kf, sacc[j], 0, 0, 0);
      }
    float sv[4][4];
#pragma unroll
    for (int j = 0; j < 4; j++)
#pragma unroll
      for (int r = 0; r < 4; r++) {
        float v = sacc[j][r];
        if (diag) {
          int kg = kt * 64 + j * 16 + l16;
          int qg = qm0 + wave * 16 + quad * 4 + r;
          if (kg > qg) v = -INFINITY;
        }
        sv[j][r] = v;
      }
    float mnew[4];
#pragma unroll
    for (int r = 0; r < 4; r++)
      mnew[r] = fmaxf(fmaxf(sv[0][r], sv[1][r]), fmaxf(sv[2][r], sv[3][r]));
#pragma unroll
    for (int off = 1; off < 16; off <<= 1)
#pragma unroll
      for (int r = 0; r < 4; r++)
        mnew[r] = fmaxf(mnew[r], __shfl_xor(mnew[r], off, 64));
    float alpha[4];
#pragma unroll
    for (int r = 0; r < 4; r++) {
      float mi = fmaxf(mrow[r], mnew[r]);
      alpha[r] = __expf(mrow[r] - mi);
      mrow[r] = mi;
    }
    float rs[4] = {0.f, 0.f, 0.f, 0.f};
#pragma unroll
    for (int j = 0; j < 4; j++)
#pragma unroll
      for (int r = 0; r < 4; r++) {
        float p2 = __expf(sv[j][r] - mrow[r]);
        rs[r] += p2;
        Pw[(j * 2 + (l16 >> 3)) * 136 + (quad * 4 + r) * 8 + (l16 & 7)] = __float2bfloat16(p2);
      }
#pragma unroll
    for (int off = 1; off < 16; off <<= 1)
#pragma unroll
      for (int r = 0; r < 4; r++)
        rs[r] += __shfl_xor(rs[r], off, 64);
#pragma unroll
    for (int r = 0; r < 4; r++) lrow[r] = lrow[r] * alpha[r] + rs[r];
#pragma unroll
    for (int jd = 0; jd < 8; jd++)
#pragma unroll
      for (int r = 0; r < 4; r++) oacc[jd][r] *= alpha[r];

    if (kt + 1 < niter) {
      __builtin_amdgcn_s_waitcnt(0xF72);  // vmcnt(2): V(kt) landed
    } else {
      __builtin_amdgcn_s_waitcnt(0xF70);  // vmcnt(0)
    }
    __builtin_amdgcn_s_barrier();                      // C: V(kt) visible

#pragma unroll
    for (int k2 = 0; k2 < 2; k2++) {
      short8 pf = *(const short8*)(Pw + (k2 * 4 + quad) * 136 + l16 * 8);
#pragma unroll
      for (int jd = 0; jd < 8; jd++) {
        short8 vf = *(const short8*)(VsBuf + (jd * 2 + k2) * 512 + lane * 8);
        oacc[jd] = __builtin_amdgcn_mfma_f32_16x16x32_bf16(pf, vf, oacc[jd], 0, 0, 0);
      }
    }
  }

  // epilogue: O / l -> yat in PACKED layout (A-operand of projection GEMM)
  float linv[4];
#pragma unroll
  for (int r = 0; r < 4; r++) linv[r] = 1.f / lrow[r];
#pragma unroll
  for (int jd = 0; jd < 8; jd++)
#pragma unroll
    for (int r = 0; r < 4; r++) {
      int row = b * Tt + qm0 + wave * 16 + quad * 4 + r;
      int c = h * Dd + jd * 16 + l16;
      yat[packed_idx(row, c)] = __float2bfloat16(oacc[jd][r] * linv[r]);
    }
}

extern "C" void kernel_launch(void* const* d_in, const int* in_sizes, int n_in,
                              void* d_out, int out_size, void* d_ws, size_t ws_size,
                              hipStream_t stream) {
  (void)in_sizes; (void)n_in; (void)out_size; (void)ws_size;
  const float* x_f      = (const float*)d_in[0];
  const float* w_qkv_f  = (const float*)d_in[1];
  const float* w_proj_f = (const float*)d_in[2];
  float* out = (float*)d_out;

  char* ws = (char*)d_ws;
  __hip_bfloat16* qkv = (__hip_bfloat16*)ws;                      // 48 MiB
  __hip_bfloat16* vt  = (__hip_bfloat16*)(ws + 50331648);         // 16 MiB
  __hip_bfloat16* yat = (__hip_bfloat16*)(ws + 67108864);         // 16 MiB (packed)
  __hip_bfloat16* xb  = (__hip_bfloat16*)(ws + 83886080);         // 16 MiB (packed)
  __hip_bfloat16* wqb = (__hip_bfloat16*)(ws + 100663296);        // 24 MiB (packed)
  __hip_bfloat16* wpb = (__hip_bfloat16*)(ws + 125829120);        // 8 MiB (packed)

  // pack-cast fp32 inputs -> bf16 packed tiles (K=2048 for all three)
  pack_cast<<<4096, 256, 0, stream>>>(x_f, xb, 1048576);       // 4096 x 2048
  pack_cast<<<6144, 256, 0, stream>>>(w_qkv_f, wqb, 1572864);  // 6144 x 2048
  pack_cast<<<2048, 256, 0, stream>>>(w_proj_f, wpb, 524288);  // 2048 x 2048

  gemm_pk8<<<dim3(24, 16), 512, 0, stream>>>(xb, wqb, qkv, 6144);
  rope_qk<<<32768, 256, 0, stream>>>(qkv);
  transpose_v<<<dim3(64, 32), 256, 0, stream>>>(qkv, vt);
  flash_attn3<<<512, 512, 0, stream>>>(qkv, vt, yat);
  gemm_pk<float><<<dim3(16, 32), 256, 0, stream>>>(yat, wpb, out, 2048, 2048);
}